// Round 11
// baseline (296.981 us; speedup 1.0000x reference)
//
#include <hip/hip_runtime.h>
#include <stdint.h>

typedef unsigned short u16;
using short8 = __attribute__((ext_vector_type(8))) short;
using f32x4  = __attribute__((ext_vector_type(4))) float;

#define NB 4
#define NN 128
#define NF 32
#define ND 64
#define NMAT (NB*ND*NN*NN)   // 4,194,304

// ---- workspace byte offsets ----
#define OFF_A     0u
#define OFF_ACC   262144u
#define OFF_AAT   262400u
#define OFF_RA    524544u
#define OFF_W     526592u
#define OFF_RM    1116416u
#define OFF_CM    1247488u
#define OFF_RX    1378560u
#define OFF_CX    1509632u
#define OFF_BF    1640960u
#define OFF_ATB   1641472u
#define OFF_WB    1772544u
#define OFF_XB    1936384u     // bf16 NMAT: X1 (layer1), overwritten by X2 (tne-L0)
#define OFF_UA    18713600u
#define OFF_UB    27102208u
#define OFF_UC    35490816u
#define OFF_UD    43879424u
#define OFF_YACC  52268032u
#define OFF_XF    (OFF_YACC)
#define OFF_EWF   (OFF_YACC + 65536u)
#define OFF_CF    (OFF_YACC + 98304u)

__device__ __forceinline__ float b2f(u16 v){
  union { uint32_t u; float f; } x; x.u = ((uint32_t)v) << 16; return x.f;
}
__device__ __forceinline__ u16 f2b(float f){
  union { uint32_t u; float f2; } x; x.f2 = f;
  uint32_t u = x.u;
  return (u16)((u + 0x7FFFu + ((u >> 16) & 1u)) >> 16);
}

#define MFMA16(a,b,c) __builtin_amdgcn_mfma_f32_16x16x32_bf16((a),(b),(c),0,0,0)

__device__ __constant__ signed char dR1[18] = {0,9,1,10,2,3,4,13,14,19,5,7,15,18,6,8,16,17};
__device__ __constant__ signed char dR2[18] = {-1,11,-1,12,-1,-1,-1,-1,-1,-1,-1,-1,-1,-1,-1,-1,-1,-1};

// ---- convert with per-block local dtype detect ----
__global__ void k_convert(const void* __restrict__ xs, const void* __restrict__ ews,
                          const void* __restrict__ c1s, const void* __restrict__ c2s,
                          const void* __restrict__ b1s, const void* __restrict__ b2s,
                          float* __restrict__ xf, float* __restrict__ ewf,
                          float* __restrict__ cf, float* __restrict__ bfv){
  __shared__ int flg;
  const u16* x16 = (const u16*)xs;
  if (threadIdx.x == 0) flg = 0;
  __syncthreads();
  int hit = 0;
  for (int k = threadIdx.x; k < 1024; k += 256){
    u16 u = x16[k];
    if (((u >> 7) & 0xFF) >= 0x90) hit = 1;
  }
  if (hit) flg = 1;
  __syncthreads();
  const int isf = flg;

  int t = blockIdx.x*256 + threadIdx.x;
  if (t >= 188544) return;
  const void* src; int idx; float* dst;
  if (t < 16384)      { src = xs;  idx = t;          dst = xf + idx; }
  else if (t < 24576) { src = ews; idx = t - 16384;  dst = ewf + idx; }
  else if (t < 106496){ src = c1s; idx = t - 24576;  dst = cf + idx; }
  else if (t < 188416){ src = c2s; idx = t - 106496; dst = cf + 81920 + idx; }
  else if (t < 188480){ src = b1s; idx = t - 188416; dst = bfv + idx; }
  else                { src = b2s; idx = t - 188480; dst = bfv + 64 + idx; }
  float v = isf ? ((const float*)src)[idx] : b2f(((const u16*)src)[idx]);
  *dst = v;
}

// ---- fused setup: scatter | makeX1 into XB ([e][ij] layout) | buildW ----
__global__ void k_setup(const int* __restrict__ ei, const int* __restrict__ bat,
                        const float* __restrict__ ewf, float* __restrict__ A, int E,
                        const float* __restrict__ xf, u16* __restrict__ XB,
                        const float* __restrict__ cf, float* __restrict__ W,
                        u16* __restrict__ Wb){
  const int bx = blockIdx.x;
  if (bx < 32){
    for (int t = bx*256 + threadIdx.x; t < E; t += 32*256){
      int s = ei[t], dnode = ei[E + t];
      int g = bat[s];
      int r = s - g*NN, c = dnode - g*NN;
      atomicAdd(&A[(g*NN + r)*NN + c], ewf[t]);
    }
  } else if (bx < 32 + 2048){
    int gid = (bx - 32)*256 + threadIdx.x;
    if (gid >= NMAT/8) return;
    int c8 = gid & 2047;           // ij-chunk (8 wide) within [e]
    int ij0 = c8*8;
    int e  = (gid >> 11) & 63;
    int b  = gid >> 17;
    int i = ij0 >> 7, j0 = ij0 & 127;
    short8 v;
    if (e < NF){
      u16 s = f2b(xf[(b*NN + i)*NF + e]);
      #pragma unroll
      for (int x = 0; x < 8; x++) v[x] = (short)s;
    } else {
      #pragma unroll
      for (int x = 0; x < 8; x++) v[x] = (short)f2b(xf[(b*NN + j0 + x)*NF + (e - NF)]);
    }
    *(short8*)(XB + ((size_t)(b*64 + e) << 14) + ij0) = v;
  } else {
    int gl = (bx - 2080)*256 + threadIdx.x;
    if (gl >= 2*1152*64) return;
    int L = gl / (1152*64);
    int rem = gl - L*1152*64;
    int row = rem >> 6, e = rem & 63;
    int slot = row >> 6, d = row & 63;
    const float* cc = cf + L*81920;
    int base = (d*64 + e)*20;
    float v = cc[base + dR1[slot]];
    if (dR2[slot] >= 0) v += cc[base + dR2[slot]];
    float scale = (slot == 9) ? 1.0f : (1.0f/128.0f);
    v *= scale;
    W[gl] = v;
    if (slot < 10)
      Wb[(((size_t)L*10 + slot)*64 + e)*64 + d] = f2b(v);
  }
}

// ---- fused A-processing: iq<8 = AAt slices | iq==8 = ATb transpose | iq==9 = rA ----
__global__ __launch_bounds__(256) void k_prepA(const float* __restrict__ A, float* __restrict__ AAt,
                                               u16* __restrict__ ATb, float* __restrict__ rA){
  const int iq = blockIdx.x, b = blockIdx.y;
  const int t = threadIdx.x;
  if (iq < 8){
    int j = t & 127, ih = t >> 7;
    const float* Ab = A + b*NN*NN;
    float acc[8] = {0,0,0,0,0,0,0,0};
    for (int k = 0; k < NN; k++){
      float aj = Ab[j*NN + k];
      #pragma unroll
      for (int ii = 0; ii < 8; ii++){
        int i = iq*16 + ih*8 + ii;
        acc[ii] += Ab[i*NN + k] * aj;
      }
    }
    #pragma unroll
    for (int ii = 0; ii < 8; ii++){
      int i = iq*16 + ih*8 + ii;
      AAt[(b*NN + i)*NN + j] = acc[ii];
    }
  } else if (iq == 8){
    __shared__ float lds[128][129];
    for (int l = 0; l < 64; l++){
      int idx = l*256 + t;
      lds[idx >> 7][idx & 127] = A[b*16384 + idx];
    }
    __syncthreads();
    for (int l = 0; l < 64; l++){
      int idx = l*256 + t;
      int r = idx >> 7, c = idx & 127;
      ATb[b*16384 + idx] = f2b(lds[c][r]);
    }
  } else {
    if (t < 128){
      const float* Ab = A + (b*NN + t)*NN;
      float s = 0.f;
      for (int j = 0; j < NN; j++) s += Ab[j];
      rA[b*NN + t] = s;
    }
  }
}

#define SJ32 72
#define SJF  69
#define SXT  72   // u16 stride for the in-mix X tile

// ---- fused: mix (bx<256, X via in-LDS transpose) | rowcol (bx>=256, XB layout) ----
__global__ __launch_bounds__(256) void k_mixrow(const u16* __restrict__ XB, const float* __restrict__ A,
    const float* __restrict__ AAt, const float* __restrict__ rA, const u16* __restrict__ Wb,
    u16* __restrict__ Ua, u16* __restrict__ Ub, u16* __restrict__ Uc, u16* __restrict__ Ud,
    float* __restrict__ Yacc,
    float* __restrict__ RM, float* __restrict__ CM,
    float* __restrict__ RX, float* __restrict__ CXv)
{
  const int b = blockIdx.y;
  const int t = threadIdx.x;

  if (blockIdx.x >= 256){
    // ---- rowcol on XB [e][ij]; accumulation order identical to R10 ----
    int d = t & 63;
    int task = (blockIdx.x - 256)*4 + (t >> 6);
    const u16* Xb_ = XB + ((size_t)(b*64 + d) << 14);
    float sm = 0.f, sx = 0.f;
    if (task < 128){
      int i = task;
      for (int j = 0; j < 128; j++){
        float xv = b2f(Xb_[i*128 + j]);
        float av = A[b*16384 + i*128 + j];
        sm += xv*av; sx += xv;
      }
      RM[(b*64 + d)*128 + i] = sm;
      RX[(b*64 + d)*128 + i] = sx;
    } else {
      int j = task - 128;
      for (int i = 0; i < 128; i++){
        float xv = b2f(Xb_[i*128 + j]);
        float av = A[b*16384 + i*128 + j];
        sm += xv*av; sx += xv;
      }
      CM[(b*64 + d)*128 + j] = sm;
      CXv[(b*64 + d)*128 + j] = sx;
    }
    return;
  }

  const int w = t >> 6, lane = t & 63;
  const int col = lane & 15, quad = lane >> 4;
  const int ij0 = blockIdx.x*64;

  __shared__ uint32_t lsb[4][32*SJ32];
  __shared__ float lsf[64*SJF];
  __shared__ u16 xtl[64*SXT];   // X tile transposed: [ij_local][e]

  // hoisted Wb fragment loads (issue before staging for latency overlap)
  short8 wa[10][2];
  #pragma unroll
  for (int s = 0; s < 10; s++){
    const u16* wp = Wb + (size_t)((s*64 + w*16 + col)*64 + quad*8);
    wa[s][0] = *(const short8*)wp;
    wa[s][1] = *(const short8*)(wp + 32);
  }

  // stage X tile: XB[e][ij0..+64] -> xtl[ij_local][e]
  {
    const int e = t >> 2, c2 = (t & 3)*2;
    const u16* xr = XB + ((size_t)(b*64 + e) << 14) + ij0;
    #pragma unroll
    for (int cc = 0; cc < 2; cc++){
      int c = c2 + cc;
      short8 v = *(const short8*)(xr + c*8);
      #pragma unroll
      for (int x = 0; x < 8; x++) xtl[(c*8 + x)*SXT + e] = (u16)v[x];
    }
  }

  float a_s[4], t_s[4], rjv[4];
  #pragma unroll
  for (int sj = 0; sj < 4; sj++){
    int ij = ij0 + sj*16 + col;
    a_s[sj] = A[b*16384 + ij];
    t_s[sj] = AAt[b*16384 + ij];
    rjv[sj] = rA[b*128 + (ij & 127)];
  }
  const float riv = rA[b*128 + (ij0 >> 7)];

  __syncthreads();   // xtl ready

  short8 xb[4][2];
  #pragma unroll
  for (int sj = 0; sj < 4; sj++){
    const u16* xp = &xtl[(sj*16 + col)*SXT + quad*8];
    xb[sj][0] = *(const short8*)xp;
    xb[sj][1] = *(const short8*)(xp + 32);
  }

  #pragma unroll
  for (int g = 0; g < 5; g++){
    const int s0_tab[5]  = {0, 2, 4, 5, 6};
    const int nsl_tab[5] = {2, 2, 1, 1, 4};
    const int s0 = s0_tab[g], nsl = nsl_tab[g];
    #pragma unroll
    for (int sj = 0; sj < 4; sj++){
      f32x4 acc[4];
      #pragma unroll
      for (int s = 0; s < 4; s++) acc[s] = (f32x4){0.f,0.f,0.f,0.f};
      #pragma unroll
      for (int s = 0; s < 4; s++){
        if (s >= nsl) break;
        acc[s] = MFMA16(wa[s0+s][0], xb[sj][0], acc[s]);
        acc[s] = MFMA16(wa[s0+s][1], xb[sj][1], acc[s]);
      }
      if (g < 4){
        float v[4];
        #pragma unroll
        for (int r = 0; r < 4; r++){
          if (g == 2 || g == 3) v[r] = acc[0][r]*a_s[sj];
          else                  v[r] = acc[0][r]*a_s[sj] + acc[1][r];
        }
        uint32_t p0 = (uint32_t)f2b(v[0]) | ((uint32_t)f2b(v[1]) << 16);
        uint32_t p1 = (uint32_t)f2b(v[2]) | ((uint32_t)f2b(v[3]) << 16);
        int ep = w*8 + quad*2;
        lsb[g][ep*SJ32 + sj*16 + col] = p0;
        lsb[g][(ep + 1)*SJ32 + sj*16 + col] = p1;
      } else {
        #pragma unroll
        for (int r = 0; r < 4; r++){
          float v = acc[0][r]*t_s[sj] + acc[1][r]*riv + acc[2][r]*rjv[sj] + acc[3][r];
          lsf[(w*16 + quad*4 + r)*SJF + sj*16 + col] = v;
        }
      }
    }
  }
  __syncthreads();

  const int eo = t >> 2, seg = t & 3;
  const int ep = eo >> 1, sh = (eo & 1)*16;
  #pragma unroll
  for (int g = 0; g < 4; g++){
    const uint32_t* lp = &lsb[g][ep*SJ32 + seg*16];
    short8 v0, v1;
    #pragma unroll
    for (int k = 0; k < 8; k++){
      v0[k] = (short)((lp[k]   >> sh) & 0xffffu);
      v1[k] = (short)((lp[8+k] >> sh) & 0xffffu);
    }
    u16* U = (g==0)?Ua:(g==1)?Ub:(g==2)?Uc:Ud;
    u16* dst = U + ((size_t)(b*64 + eo) << 14) + ij0 + seg*16;
    *(short8*)dst = v0;
    *(short8*)(dst + 8) = v1;
  }
  {
    const float* fp = &lsf[eo*SJF + seg*16];
    float* dst = Yacc + ((size_t)(b*64 + eo) << 14) + ij0 + seg*16;
    #pragma unroll
    for (int q = 0; q < 4; q++)
      *(float4*)(dst + q*4) = make_float4(fp[q*4], fp[q*4+1], fp[q*4+2], fp[q*4+3]);
  }
}

#define SLT 68   // uint32 stride for in-kernel transpose staging

// ---- fused: in-LDS transposes + four A-products + Yacc + broadcast + bias + sigmoid/reduce ----
__global__ __launch_bounds__(256) void k_tne(const u16* __restrict__ ATb,
    const u16* __restrict__ Ua, const u16* __restrict__ Ub,
    const u16* __restrict__ Uc, const u16* __restrict__ Ud,
    const float* __restrict__ Yacc, const float* __restrict__ W,
    const float* __restrict__ RM, const float* __restrict__ CM,
    const float* __restrict__ RX, const float* __restrict__ CXv,
    const float* __restrict__ bias, u16* __restrict__ Xout, float* __restrict__ acc4, int last)
{
  const int nh = blockIdx.x, be = blockIdx.y;
  const int b = be >> 6, e = be & 63;
  const int t = threadIdx.x, wave = t >> 6, lane = t & 63;
  const int col = lane & 15, quad = lane >> 4;
  const int m0 = (wave >> 1)*64;
  const int n0 = nh*64 + (wave & 1)*32;
  const int nb0 = nh*64;

  __shared__ uint32_t uls[128*SLT];
  __shared__ uint32_t ubl[64*SLT];
  __shared__ float radd[128], cadd[128];
  __shared__ float red[4];

  if (t < 128){
    int i = t; float s = 0.f;
    for (int d = 0; d < ND; d++){
      int v = (b*ND + d)*NN + i;
      s += W[(640 + d)*64 + e]*RM[v] + W[(704 + d)*64 + e]*CM[v]
         + W[(768 + d)*64 + e]*RX[v] + W[(832 + d)*64 + e]*CXv[v];
    }
    radd[i] = s;
  } else {
    int j = t - 128; float s = 0.f;
    for (int d = 0; d < ND; d++){
      int v = (b*ND + d)*NN + j;
      s += W[(896 + d)*64 + e]*RM[v] + W[(960 + d)*64 + e]*CM[v]
         + W[(1024 + d)*64 + e]*RX[v] + W[(1088 + d)*64 + e]*CXv[v];
    }
    cadd[j] = s;
  }

  const u16* ua = Ua + ((size_t)be << 14);
  const u16* ub = Ub + ((size_t)be << 14);
  {
    const int kp = t >> 2;
    #pragma unroll
    for (int it = 0; it < 4; it++){
      int mo = it*4 + (t & 3);
      short8 r0 = *(const short8*)(ua + (2*kp)*128 + mo*8);
      short8 r1 = *(const short8*)(ua + (2*kp + 1)*128 + mo*8);
      #pragma unroll
      for (int x = 0; x < 8; x++)
        uls[(mo*8 + x)*SLT + kp] = ((uint32_t)(u16)r0[x]) | (((uint32_t)(u16)r1[x]) << 16);
    }
    #pragma unroll
    for (int it = 0; it < 2; it++){
      int no = it*4 + (t & 3);
      short8 r0 = *(const short8*)(ub + (2*kp)*128 + nb0 + no*8);
      short8 r1 = *(const short8*)(ub + (2*kp + 1)*128 + nb0 + no*8);
      #pragma unroll
      for (int x = 0; x < 8; x++)
        ubl[(no*8 + x)*SLT + kp] = ((uint32_t)(u16)r0[x]) | (((uint32_t)(u16)r1[x]) << 16);
    }
  }
  __syncthreads();

  f32x4 acc[4][2];
  #pragma unroll
  for (int mt = 0; mt < 4; mt++)
    #pragma unroll
    for (int nt = 0; nt < 2; nt++)
      acc[mt][nt] = (f32x4){0.f,0.f,0.f,0.f};

  const u16* at = ATb + ((size_t)b << 14);
  short8 at_n[4][2];
  #pragma unroll
  for (int kq = 0; kq < 4; kq++){
    int k0 = kq*32 + quad*8;
    at_n[kq][0] = *(const short8*)(at + (n0 + col)*128 + k0);
    at_n[kq][1] = *(const short8*)(at + (n0 + 16 + col)*128 + k0);
  }

  #pragma unroll
  for (int kq = 0; kq < 4; kq++){
    int kd = kq*16 + quad*4;
    #pragma unroll
    for (int mt = 0; mt < 4; mt++){
      short8 af = *(const short8*)&uls[(m0 + mt*16 + col)*SLT + kd];
      acc[mt][0] = MFMA16(af, at_n[kq][0], acc[mt][0]);
      acc[mt][1] = MFMA16(af, at_n[kq][1], acc[mt][1]);
    }
  }
  #pragma unroll
  for (int kq = 0; kq < 4; kq++){
    int k0 = kq*32 + quad*8, kd = kq*16 + quad*4;
    short8 bf0 = *(const short8*)&ubl[((wave & 1)*32 + 0*16 + col)*SLT + kd];
    short8 bf1 = *(const short8*)&ubl[((wave & 1)*32 + 1*16 + col)*SLT + kd];
    #pragma unroll
    for (int mt = 0; mt < 4; mt++){
      short8 af = *(const short8*)(at + (m0 + mt*16 + col)*128 + k0);
      acc[mt][0] = MFMA16(af, bf0, acc[mt][0]);
      acc[mt][1] = MFMA16(af, bf1, acc[mt][1]);
    }
  }
  {
    const u16* uc = Uc + ((size_t)be << 14);
    #pragma unroll
    for (int kq = 0; kq < 4; kq++){
      int k0 = kq*32 + quad*8;
      #pragma unroll
      for (int mt = 0; mt < 4; mt++){
        short8 af = *(const short8*)(uc + (m0 + mt*16 + col)*128 + k0);
        acc[mt][0] = MFMA16(af, at_n[kq][0], acc[mt][0]);
        acc[mt][1] = MFMA16(af, at_n[kq][1], acc[mt][1]);
      }
    }
  }
  {
    const u16* ud = Ud + ((size_t)be << 14);
    #pragma unroll
    for (int kq = 0; kq < 4; kq++){
      int k0 = kq*32 + quad*8;
      short8 bf0 = *(const short8*)(ud + (n0 + col)*128 + k0);
      short8 bf1 = *(const short8*)(ud + (n0 + 16 + col)*128 + k0);
      #pragma unroll
      for (int mt = 0; mt < 4; mt++){
        short8 af = *(const short8*)(at + (m0 + mt*16 + col)*128 + k0);
        acc[mt][0] = MFMA16(af, bf0, acc[mt][0]);
        acc[mt][1] = MFMA16(af, bf1, acc[mt][1]);
      }
    }
  }
  __syncthreads();

  uint32_t* stg = uls;
  const float bv = bias[e];
  const float* Y = Yacc + ((size_t)be << 14);
  if (!last){
    #pragma unroll
    for (int mt = 0; mt < 4; mt++)
      #pragma unroll
      for (int nt = 0; nt < 2; nt++)
        #pragma unroll
        for (int rp = 0; rp < 2; rp++){
          uint32_t p = 0;
          #pragma unroll
          for (int h = 0; h < 2; h++){
            int r = rp*2 + h;
            int row = m0 + mt*16 + quad*4 + r;
            int cn = n0 + nt*16 + col;
            float v = acc[mt][nt][r] + Y[row*128 + cn] + radd[row] + cadd[cn] + bv;
            v = 1.f/(1.f + __expf(-v));
            p |= ((uint32_t)f2b(v)) << (16*h);
          }
          int ipair = (m0 + mt*16 + quad*4) >> 1;
          stg[(ipair + rp)*SLT + (wave & 1)*32 + nt*16 + col] = p;
        }
    __syncthreads();
    const uint32_t* lp = &stg[(t >> 2)*SLT + (t & 1)*32];
    const int sh = ((t >> 1) & 1)*16;
    u16* dst = Xout + ((size_t)be << 14) + (size_t)(t >> 1)*128 + nh*64 + (t & 1)*32;
    #pragma unroll
    for (int q2 = 0; q2 < 4; q2++){
      short8 v;
      #pragma unroll
      for (int k = 0; k < 8; k++) v[k] = (short)((lp[q2*8 + k] >> sh) & 0xffffu);
      *(short8*)(dst + q2*8) = v;
    }
  } else {
    float loc = 0.f;
    #pragma unroll
    for (int mt = 0; mt < 4; mt++)
      #pragma unroll
      for (int nt = 0; nt < 2; nt++)
        #pragma unroll
        for (int r = 0; r < 4; r++){
          int row = m0 + mt*16 + quad*4 + r;
          int cn = n0 + nt*16 + col;
          loc += acc[mt][nt][r] + Y[row*128 + cn] + radd[row] + cadd[cn] + bv;
        }
    for (int off = 32; off > 0; off >>= 1) loc += __shfl_down(loc, off, 64);
    if (lane == 0) red[wave] = loc;
    __syncthreads();
    if (t == 0) atomicAdd(&acc4[b], red[0] + red[1] + red[2] + red[3]);
  }
}

// ---- finish with inline dtype detect ----
__global__ void k_finish(const float* __restrict__ acc4, const u16* __restrict__ x16,
                         void* __restrict__ out){
  __shared__ int flg;
  int t = threadIdx.x;
  if (t == 0) flg = 0;
  __syncthreads();
  int hit = 0;
  for (int k = t; k < 512; k += 64){
    u16 u = x16[k];
    if (((u >> 7) & 0xFF) >= 0x90) hit = 1;
  }
  if (hit) flg = 1;
  __syncthreads();
  if (t < NB){
    float v = acc4[t] * (1.0f/1048576.0f);
    if (flg) ((float*)out)[t] = v;
    else     ((u16*)out)[t] = f2b(v);
  }
}

extern "C" void kernel_launch(void* const* d_in, const int* in_sizes, int n_in,
                              void* d_out, int out_size, void* d_ws, size_t ws_size,
                              hipStream_t stream)
{
  const void* x   = d_in[0];
  const void* ew  = d_in[1];
  const void* c1  = d_in[2];
  const void* b1  = d_in[3];
  const void* c2  = d_in[4];
  const void* b2  = d_in[5];
  const int* ei  = (const int*)d_in[6];
  const int* bat = (const int*)d_in[7];
  const int E = in_sizes[1];

  char* wsb = (char*)d_ws;
  float* A    = (float*)(wsb + OFF_A);
  float* acc4 = (float*)(wsb + OFF_ACC);
  float* AAt  = (float*)(wsb + OFF_AAT);
  float* rA   = (float*)(wsb + OFF_RA);
  float* W    = (float*)(wsb + OFF_W);
  float* RM   = (float*)(wsb + OFF_RM);
  float* CM   = (float*)(wsb + OFF_CM);
  float* RX   = (float*)(wsb + OFF_RX);
  float* CXv  = (float*)(wsb + OFF_CX);
  float* bfv  = (float*)(wsb + OFF_BF);
  u16* ATb = (u16*)(wsb + OFF_ATB);
  u16* Wb  = (u16*)(wsb + OFF_WB);
  u16* XB  = (u16*)(wsb + OFF_XB);
  u16* Ua  = (u16*)(wsb + OFF_UA);
  u16* Ub  = (u16*)(wsb + OFF_UB);
  u16* Uc  = (u16*)(wsb + OFF_UC);
  u16* Ud  = (u16*)(wsb + OFF_UD);
  float* Yacc = (float*)(wsb + OFF_YACC);
  float* xf   = (float*)(wsb + OFF_XF);
  float* ewf  = (float*)(wsb + OFF_EWF);
  float* cf   = (float*)(wsb + OFF_CF);

  hipMemsetAsync(wsb, 0, OFF_AAT, stream);   // zero A + acc4

  k_convert<<<dim3(737), dim3(256), 0, stream>>>(x, ew, c1, c2, b1, b2, xf, ewf, cf, bfv);
  k_setup<<<dim3(2656), dim3(256), 0, stream>>>(ei, bat, ewf, A, E, xf, XB, cf, W, Wb);
  k_prepA<<<dim3(10, NB), dim3(256), 0, stream>>>(A, AAt, ATb, rA);

  for (int L = 0; L < 2; L++){
    const float* Wl = W + (size_t)L*1152*64;
    const u16*  Wbl = Wb + (size_t)L*10*64*64;
    k_mixrow<<<dim3(320, NB), dim3(256), 0, stream>>>(XB, A, AAt, rA, Wbl,
                                                      Ua, Ub, Uc, Ud, Yacc, RM, CM, RX, CXv);
    k_tne<<<dim3(2, 256), dim3(256), 0, stream>>>(ATb, Ua, Ub, Uc, Ud, Yacc, Wl,
                                                  RM, CM, RX, CXv, bfv + L*64, XB, acc4, L);
  }
  k_finish<<<dim3(1), dim3(64), 0, stream>>>(acc4, (const u16*)x, d_out);
}

// Round 12
// 236.563 us; speedup vs baseline: 1.2554x; 1.2554x over previous
//
#include <hip/hip_runtime.h>
#include <stdint.h>

typedef unsigned short u16;
using short8 = __attribute__((ext_vector_type(8))) short;
using f32x4  = __attribute__((ext_vector_type(4))) float;

#define NB 4
#define NN 128
#define NF 32
#define ND 64
#define NMAT (NB*ND*NN*NN)   // 4,194,304

// ---- workspace byte offsets ----
#define OFF_A     0u
#define OFF_ACC   262144u
#define OFF_AAT   262400u
#define OFF_RA    524544u
#define OFF_W     526592u
#define OFF_RM    1116416u
#define OFF_CM    1247488u
#define OFF_RX    1378560u
#define OFF_CX    1509632u
#define OFF_BF    1640960u
#define OFF_ATB   1641472u
#define OFF_WB    1772544u
#define OFF_X2    1936384u
#define OFF_XT    10324992u
#define OFF_UA    18713600u
#define OFF_UB    27102208u
#define OFF_UC    35490816u
#define OFF_UD    43879424u
#define OFF_YACC  52268032u
#define OFF_XF    (OFF_YACC)
#define OFF_EWF   (OFF_YACC + 65536u)
#define OFF_CF    (OFF_YACC + 98304u)

__device__ __forceinline__ float b2f(u16 v){
  union { uint32_t u; float f; } x; x.u = ((uint32_t)v) << 16; return x.f;
}
__device__ __forceinline__ u16 f2b(float f){
  union { uint32_t u; float f2; } x; x.f2 = f;
  uint32_t u = x.u;
  return (u16)((u + 0x7FFFu + ((u >> 16) & 1u)) >> 16);
}

#define MFMA16(a,b,c) __builtin_amdgcn_mfma_f32_16x16x32_bf16((a),(b),(c),0,0,0)

__device__ __constant__ signed char dR1[18] = {0,9,1,10,2,3,4,13,14,19,5,7,15,18,6,8,16,17};
__device__ __constant__ signed char dR2[18] = {-1,11,-1,12,-1,-1,-1,-1,-1,-1,-1,-1,-1,-1,-1,-1,-1,-1};

// ---- convert with per-block local dtype detect ----
__global__ void k_convert(const void* __restrict__ xs, const void* __restrict__ ews,
                          const void* __restrict__ c1s, const void* __restrict__ c2s,
                          const void* __restrict__ b1s, const void* __restrict__ b2s,
                          float* __restrict__ xf, float* __restrict__ ewf,
                          float* __restrict__ cf, float* __restrict__ bfv){
  __shared__ int flg;
  const u16* x16 = (const u16*)xs;
  if (threadIdx.x == 0) flg = 0;
  __syncthreads();
  int hit = 0;
  for (int k = threadIdx.x; k < 1024; k += 256){
    u16 u = x16[k];
    if (((u >> 7) & 0xFF) >= 0x90) hit = 1;
  }
  if (hit) flg = 1;
  __syncthreads();
  const int isf = flg;

  int t = blockIdx.x*256 + threadIdx.x;
  if (t >= 188544) return;
  const void* src; int idx; float* dst;
  if (t < 16384)      { src = xs;  idx = t;          dst = xf + idx; }
  else if (t < 24576) { src = ews; idx = t - 16384;  dst = ewf + idx; }
  else if (t < 106496){ src = c1s; idx = t - 24576;  dst = cf + idx; }
  else if (t < 188416){ src = c2s; idx = t - 106496; dst = cf + 81920 + idx; }
  else if (t < 188480){ src = b1s; idx = t - 188416; dst = bfv + idx; }
  else                { src = b2s; idx = t - 188480; dst = bfv + 64 + idx; }
  float v = isf ? ((const float*)src)[idx] : b2f(((const u16*)src)[idx]);
  *dst = v;
}

// ---- fused setup: scatter | makeXt1 | buildW ----
__global__ void k_setup(const int* __restrict__ ei, const int* __restrict__ bat,
                        const float* __restrict__ ewf, float* __restrict__ A, int E,
                        const float* __restrict__ xf, u16* __restrict__ Xt,
                        const float* __restrict__ cf, float* __restrict__ W,
                        u16* __restrict__ Wb){
  const int bx = blockIdx.x;
  if (bx < 32){
    for (int t = bx*256 + threadIdx.x; t < E; t += 32*256){
      int s = ei[t], dnode = ei[E + t];
      int g = bat[s];
      int r = s - g*NN, c = dnode - g*NN;
      atomicAdd(&A[(g*NN + r)*NN + c], ewf[t]);
    }
  } else if (bx < 32 + 2048){
    int gid = (bx - 32)*256 + threadIdx.x;
    if (gid >= NMAT/8) return;
    int d0 = (gid & 7)*8;
    int ij = (gid >> 3) & 16383;
    int b  = gid >> 17;
    int i = ij >> 7, j = ij & 127;
    const float* src = (d0 < NF) ? &xf[(b*NN + i)*NF + d0] : &xf[(b*NN + j)*NF + (d0 - NF)];
    float4 f0 = *(const float4*)src;
    float4 f1 = *(const float4*)(src + 4);
    short8 v;
    v[0]=(short)f2b(f0.x); v[1]=(short)f2b(f0.y); v[2]=(short)f2b(f0.z); v[3]=(short)f2b(f0.w);
    v[4]=(short)f2b(f1.x); v[5]=(short)f2b(f1.y); v[6]=(short)f2b(f1.z); v[7]=(short)f2b(f1.w);
    *(short8*)(Xt + ((size_t)(b*16384 + ij))*64 + d0) = v;
  } else {
    int gl = (bx - 2080)*256 + threadIdx.x;
    if (gl >= 2*1152*64) return;
    int L = gl / (1152*64);
    int rem = gl - L*1152*64;
    int row = rem >> 6, e = rem & 63;
    int slot = row >> 6, d = row & 63;
    const float* cc = cf + L*81920;
    int base = (d*64 + e)*20;
    float v = cc[base + dR1[slot]];
    if (dR2[slot] >= 0) v += cc[base + dR2[slot]];
    float scale = (slot == 9) ? 1.0f : (1.0f/128.0f);
    v *= scale;
    W[gl] = v;
    if (slot < 10)
      Wb[(((size_t)L*10 + slot)*64 + e)*64 + d] = f2b(v);
  }
}

// ---- fused A-processing: iq<8 = AAt slices | iq==8 = ATb transpose | iq==9 = rA ----
__global__ __launch_bounds__(256) void k_prepA(const float* __restrict__ A, float* __restrict__ AAt,
                                               u16* __restrict__ ATb, float* __restrict__ rA){
  const int iq = blockIdx.x, b = blockIdx.y;
  const int t = threadIdx.x;
  if (iq < 8){
    int j = t & 127, ih = t >> 7;
    const float* Ab = A + b*NN*NN;
    float acc[8] = {0,0,0,0,0,0,0,0};
    for (int k = 0; k < NN; k++){
      float aj = Ab[j*NN + k];
      #pragma unroll
      for (int ii = 0; ii < 8; ii++){
        int i = iq*16 + ih*8 + ii;
        acc[ii] += Ab[i*NN + k] * aj;
      }
    }
    #pragma unroll
    for (int ii = 0; ii < 8; ii++){
      int i = iq*16 + ih*8 + ii;
      AAt[(b*NN + i)*NN + j] = acc[ii];
    }
  } else if (iq == 8){
    __shared__ float lds[128][129];
    for (int l = 0; l < 64; l++){
      int idx = l*256 + t;
      lds[idx >> 7][idx & 127] = A[b*16384 + idx];
    }
    __syncthreads();
    for (int l = 0; l < 64; l++){
      int idx = l*256 + t;
      int r = idx >> 7, c = idx & 127;
      ATb[b*16384 + idx] = f2b(lds[c][r]);
    }
  } else {
    if (t < 128){
      const float* Ab = A + (b*NN + t)*NN;
      float s = 0.f;
      for (int j = 0; j < NN; j++) s += Ab[j];
      rA[b*NN + t] = s;
    }
  }
}

// ---- X2[b][e][ij] -> Xt[b][ij][e] via LDS tiles ----
__global__ __launch_bounds__(256) void k_xt(const u16* __restrict__ X, u16* __restrict__ Xt){
  int b = blockIdx.y;
  int ij0 = blockIdx.x*64;
  __shared__ u16 lds[64][65];
  int t = threadIdx.x;
  #pragma unroll
  for (int l = 0; l < 2; l++){
    int idx = l*2048 + t*8;
    int d = idx >> 6, c = idx & 63;
    const u16* p = X + ((size_t)(b*64 + d))*16384 + ij0 + c;
    short8 v = *(const short8*)p;
    #pragma unroll
    for (int k = 0; k < 8; k++) lds[d][c + k] = (u16)v[k];
  }
  __syncthreads();
  #pragma unroll
  for (int l = 0; l < 2; l++){
    int idx = l*2048 + t*8;
    int r = idx >> 6, c = idx & 63;
    short8 v;
    #pragma unroll
    for (int k = 0; k < 8; k++) v[k] = (short)lds[c + k][r];
    *(short8*)(Xt + ((size_t)(b*16384 + ij0 + r))*64 + c) = v;
  }
}

#define SJ32 72
#define SJF  69

// ---- fused: mix (bx<256) | rowcol (bx>=256) ----
__global__ __launch_bounds__(256) void k_mixrow(const u16* __restrict__ Xt, const float* __restrict__ A,
    const float* __restrict__ AAt, const float* __restrict__ rA, const u16* __restrict__ Wb,
    u16* __restrict__ Ua, u16* __restrict__ Ub, u16* __restrict__ Uc, u16* __restrict__ Ud,
    float* __restrict__ Yacc,
    float* __restrict__ RM, float* __restrict__ CM,
    float* __restrict__ RX, float* __restrict__ CXv)
{
  const int b = blockIdx.y;
  const int t = threadIdx.x;

  if (blockIdx.x >= 256){
    int d = t & 63;
    int task = (blockIdx.x - 256)*4 + (t >> 6);
    float sm = 0.f, sx = 0.f;
    if (task < 128){
      int i = task;
      for (int j = 0; j < 128; j++){
        float xv = b2f(Xt[((size_t)(b*16384 + i*128 + j))*64 + d]);
        float av = A[b*16384 + i*128 + j];
        sm += xv*av; sx += xv;
      }
      RM[(b*64 + d)*128 + i] = sm;
      RX[(b*64 + d)*128 + i] = sx;
    } else {
      int j = task - 128;
      for (int i = 0; i < 128; i++){
        float xv = b2f(Xt[((size_t)(b*16384 + i*128 + j))*64 + d]);
        float av = A[b*16384 + i*128 + j];
        sm += xv*av; sx += xv;
      }
      CM[(b*64 + d)*128 + j] = sm;
      CXv[(b*64 + d)*128 + j] = sx;
    }
    return;
  }

  const int w = t >> 6, lane = t & 63;
  const int col = lane & 15, quad = lane >> 4;
  const int ij0 = blockIdx.x*64;

  __shared__ uint32_t lsb[4][32*SJ32];
  __shared__ float lsf[64*SJF];

  short8 wa[10][2];
  #pragma unroll
  for (int s = 0; s < 10; s++){
    const u16* wp = Wb + (size_t)((s*64 + w*16 + col)*64 + quad*8);
    wa[s][0] = *(const short8*)wp;
    wa[s][1] = *(const short8*)(wp + 32);
  }
  short8 xb[4][2];
  #pragma unroll
  for (int sj = 0; sj < 4; sj++){
    const u16* xp = Xt + ((size_t)(b*16384 + ij0 + sj*16 + col))*64 + quad*8;
    xb[sj][0] = *(const short8*)xp;
    xb[sj][1] = *(const short8*)(xp + 32);
  }
  float a_s[4], t_s[4], rjv[4];
  #pragma unroll
  for (int sj = 0; sj < 4; sj++){
    int ij = ij0 + sj*16 + col;
    a_s[sj] = A[b*16384 + ij];
    t_s[sj] = AAt[b*16384 + ij];
    rjv[sj] = rA[b*128 + (ij & 127)];
  }
  const float riv = rA[b*128 + (ij0 >> 7)];

  #pragma unroll
  for (int g = 0; g < 5; g++){
    const int s0_tab[5]  = {0, 2, 4, 5, 6};
    const int nsl_tab[5] = {2, 2, 1, 1, 4};
    const int s0 = s0_tab[g], nsl = nsl_tab[g];
    #pragma unroll
    for (int sj = 0; sj < 4; sj++){
      f32x4 acc[4];
      #pragma unroll
      for (int s = 0; s < 4; s++) acc[s] = (f32x4){0.f,0.f,0.f,0.f};
      #pragma unroll
      for (int s = 0; s < 4; s++){
        if (s >= nsl) break;
        acc[s] = MFMA16(wa[s0+s][0], xb[sj][0], acc[s]);
        acc[s] = MFMA16(wa[s0+s][1], xb[sj][1], acc[s]);
      }
      if (g < 4){
        float v[4];
        #pragma unroll
        for (int r = 0; r < 4; r++){
          if (g == 2 || g == 3) v[r] = acc[0][r]*a_s[sj];
          else                  v[r] = acc[0][r]*a_s[sj] + acc[1][r];
        }
        uint32_t p0 = (uint32_t)f2b(v[0]) | ((uint32_t)f2b(v[1]) << 16);
        uint32_t p1 = (uint32_t)f2b(v[2]) | ((uint32_t)f2b(v[3]) << 16);
        int ep = w*8 + quad*2;
        lsb[g][ep*SJ32 + sj*16 + col] = p0;
        lsb[g][(ep + 1)*SJ32 + sj*16 + col] = p1;
      } else {
        #pragma unroll
        for (int r = 0; r < 4; r++){
          float v = acc[0][r]*t_s[sj] + acc[1][r]*riv + acc[2][r]*rjv[sj] + acc[3][r];
          lsf[(w*16 + quad*4 + r)*SJF + sj*16 + col] = v;
        }
      }
    }
  }
  __syncthreads();

  const int eo = t >> 2, seg = t & 3;
  const int ep = eo >> 1, sh = (eo & 1)*16;
  #pragma unroll
  for (int g = 0; g < 4; g++){
    const uint32_t* lp = &lsb[g][ep*SJ32 + seg*16];
    short8 v0, v1;
    #pragma unroll
    for (int k = 0; k < 8; k++){
      v0[k] = (short)((lp[k]   >> sh) & 0xffffu);
      v1[k] = (short)((lp[8+k] >> sh) & 0xffffu);
    }
    u16* U = (g==0)?Ua:(g==1)?Ub:(g==2)?Uc:Ud;
    u16* dst = U + ((size_t)(b*64 + eo) << 14) + ij0 + seg*16;
    *(short8*)dst = v0;
    *(short8*)(dst + 8) = v1;
  }
  {
    const float* fp = &lsf[eo*SJF + seg*16];
    float* dst = Yacc + ((size_t)(b*64 + eo) << 14) + ij0 + seg*16;
    #pragma unroll
    for (int q = 0; q < 4; q++)
      *(float4*)(dst + q*4) = make_float4(fp[q*4], fp[q*4+1], fp[q*4+2], fp[q*4+3]);
  }
}

#define SLT 68   // uint32 stride for in-kernel transpose staging (b128 reads 2-way max)

// ---- fused: in-LDS transposes + four A-products + Yacc + broadcast + bias + sigmoid/reduce ----
__global__ __launch_bounds__(256) void k_tne(const u16* __restrict__ ATb,
    const u16* __restrict__ Ua, const u16* __restrict__ Ub,
    const u16* __restrict__ Uc, const u16* __restrict__ Ud,
    const float* __restrict__ Yacc, const float* __restrict__ W,
    const float* __restrict__ RM, const float* __restrict__ CM,
    const float* __restrict__ RX, const float* __restrict__ CXv,
    const float* __restrict__ bias, u16* __restrict__ Xout, float* __restrict__ acc4, int last)
{
  const int nh = blockIdx.x, be = blockIdx.y;
  const int b = be >> 6, e = be & 63;
  const int t = threadIdx.x, wave = t >> 6, lane = t & 63;
  const int col = lane & 15, quad = lane >> 4;
  const int m0 = (wave >> 1)*64;
  const int n0 = nh*64 + (wave & 1)*32;
  const int nb0 = nh*64;

  __shared__ uint32_t uls[128*SLT];   // uat (packed bf16 pairs); stg aliases after MFMA
  __shared__ uint32_t ubl[64*SLT];    // ubt (packed bf16 pairs)
  __shared__ float radd[128], cadd[128];
  __shared__ float red[4];

  if (t < 128){
    int i = t; float s = 0.f;
    for (int d = 0; d < ND; d++){
      int v = (b*ND + d)*NN + i;
      s += W[(640 + d)*64 + e]*RM[v] + W[(704 + d)*64 + e]*CM[v]
         + W[(768 + d)*64 + e]*RX[v] + W[(832 + d)*64 + e]*CXv[v];
    }
    radd[i] = s;
  } else {
    int j = t - 128; float s = 0.f;
    for (int d = 0; d < ND; d++){
      int v = (b*ND + d)*NN + j;
      s += W[(896 + d)*64 + e]*RM[v] + W[(960 + d)*64 + e]*CM[v]
         + W[(1024 + d)*64 + e]*RX[v] + W[(1088 + d)*64 + e]*CXv[v];
    }
    cadd[j] = s;
  }

  const u16* ua = Ua + ((size_t)be << 14);
  const u16* ub = Ub + ((size_t)be << 14);
  {
    const int kp = t >> 2;               // 0..63
    #pragma unroll
    for (int it = 0; it < 4; it++){
      int mo = it*4 + (t & 3);           // 0..15
      short8 r0 = *(const short8*)(ua + (2*kp)*128 + mo*8);
      short8 r1 = *(const short8*)(ua + (2*kp + 1)*128 + mo*8);
      #pragma unroll
      for (int x = 0; x < 8; x++)
        uls[(mo*8 + x)*SLT + kp] = ((uint32_t)(u16)r0[x]) | (((uint32_t)(u16)r1[x]) << 16);
    }
    #pragma unroll
    for (int it = 0; it < 2; it++){
      int no = it*4 + (t & 3);           // 0..7
      short8 r0 = *(const short8*)(ub + (2*kp)*128 + nb0 + no*8);
      short8 r1 = *(const short8*)(ub + (2*kp + 1)*128 + nb0 + no*8);
      #pragma unroll
      for (int x = 0; x < 8; x++)
        ubl[(no*8 + x)*SLT + kp] = ((uint32_t)(u16)r0[x]) | (((uint32_t)(u16)r1[x]) << 16);
    }
  }
  __syncthreads();   // uat/ubt + radd/cadd ready

  f32x4 acc[4][2];
  #pragma unroll
  for (int mt = 0; mt < 4; mt++)
    #pragma unroll
    for (int nt = 0; nt < 2; nt++)
      acc[mt][nt] = (f32x4){0.f,0.f,0.f,0.f};

  const u16* at = ATb + ((size_t)b << 14);
  short8 at_n[4][2];
  #pragma unroll
  for (int kq = 0; kq < 4; kq++){
    int k0 = kq*32 + quad*8;
    at_n[kq][0] = *(const short8*)(at + (n0 + col)*128 + k0);
    at_n[kq][1] = *(const short8*)(at + (n0 + 16 + col)*128 + k0);
  }

  // f0: Ua^T · A   (sa from LDS uat)
  #pragma unroll
  for (int kq = 0; kq < 4; kq++){
    int kd = kq*16 + quad*4;
    #pragma unroll
    for (int mt = 0; mt < 4; mt++){
      short8 af = *(const short8*)&uls[(m0 + mt*16 + col)*SLT + kd];
      acc[mt][0] = MFMA16(af, at_n[kq][0], acc[mt][0]);
      acc[mt][1] = MFMA16(af, at_n[kq][1], acc[mt][1]);
    }
  }
  // f1: A^T · Ub   (rb from LDS ubt)
  #pragma unroll
  for (int kq = 0; kq < 4; kq++){
    int k0 = kq*32 + quad*8, kd = kq*16 + quad*4;
    short8 bf0 = *(const short8*)&ubl[((wave & 1)*32 + 0*16 + col)*SLT + kd];
    short8 bf1 = *(const short8*)&ubl[((wave & 1)*32 + 1*16 + col)*SLT + kd];
    #pragma unroll
    for (int mt = 0; mt < 4; mt++){
      short8 af = *(const short8*)(at + (m0 + mt*16 + col)*128 + k0);
      acc[mt][0] = MFMA16(af, bf0, acc[mt][0]);
      acc[mt][1] = MFMA16(af, bf1, acc[mt][1]);
    }
  }
  // f2: Uc · A
  {
    const u16* uc = Uc + ((size_t)be << 14);
    #pragma unroll
    for (int kq = 0; kq < 4; kq++){
      int k0 = kq*32 + quad*8;
      #pragma unroll
      for (int mt = 0; mt < 4; mt++){
        short8 af = *(const short8*)(uc + (m0 + mt*16 + col)*128 + k0);
        acc[mt][0] = MFMA16(af, at_n[kq][0], acc[mt][0]);
        acc[mt][1] = MFMA16(af, at_n[kq][1], acc[mt][1]);
      }
    }
  }
  // f3: (Ud · A)^T
  {
    const u16* ud = Ud + ((size_t)be << 14);
    #pragma unroll
    for (int kq = 0; kq < 4; kq++){
      int k0 = kq*32 + quad*8;
      short8 bf0 = *(const short8*)(ud + (n0 + col)*128 + k0);
      short8 bf1 = *(const short8*)(ud + (n0 + 16 + col)*128 + k0);
      #pragma unroll
      for (int mt = 0; mt < 4; mt++){
        short8 af = *(const short8*)(at + (m0 + mt*16 + col)*128 + k0);
        acc[mt][0] = MFMA16(af, bf0, acc[mt][0]);
        acc[mt][1] = MFMA16(af, bf1, acc[mt][1]);
      }
    }
  }
  __syncthreads();   // all LDS frag reads done -> uls reusable as stg

  uint32_t* stg = uls;
  const float bv = bias[e];
  const float* Y = Yacc + ((size_t)be << 14);
  if (!last){
    #pragma unroll
    for (int mt = 0; mt < 4; mt++)
      #pragma unroll
      for (int nt = 0; nt < 2; nt++)
        #pragma unroll
        for (int rp = 0; rp < 2; rp++){
          uint32_t p = 0;
          #pragma unroll
          for (int h = 0; h < 2; h++){
            int r = rp*2 + h;
            int row = m0 + mt*16 + quad*4 + r;
            int cn = n0 + nt*16 + col;
            float v = acc[mt][nt][r] + Y[row*128 + cn] + radd[row] + cadd[cn] + bv;
            v = 1.f/(1.f + __expf(-v));
            p |= ((uint32_t)f2b(v)) << (16*h);
          }
          int ipair = (m0 + mt*16 + quad*4) >> 1;
          stg[(ipair + rp)*SLT + (wave & 1)*32 + nt*16 + col] = p;
        }
    __syncthreads();
    const uint32_t* lp = &stg[(t >> 2)*SLT + (t & 1)*32];
    const int sh = ((t >> 1) & 1)*16;
    u16* dst = Xout + ((size_t)be << 14) + (size_t)(t >> 1)*128 + nh*64 + (t & 1)*32;
    #pragma unroll
    for (int q2 = 0; q2 < 4; q2++){
      short8 v;
      #pragma unroll
      for (int k = 0; k < 8; k++) v[k] = (short)((lp[q2*8 + k] >> sh) & 0xffffu);
      *(short8*)(dst + q2*8) = v;
    }
  } else {
    float loc = 0.f;
    #pragma unroll
    for (int mt = 0; mt < 4; mt++)
      #pragma unroll
      for (int nt = 0; nt < 2; nt++)
        #pragma unroll
        for (int r = 0; r < 4; r++){
          int row = m0 + mt*16 + quad*4 + r;
          int cn = n0 + nt*16 + col;
          loc += acc[mt][nt][r] + Y[row*128 + cn] + radd[row] + cadd[cn] + bv;
        }
    for (int off = 32; off > 0; off >>= 1) loc += __shfl_down(loc, off, 64);
    if (lane == 0) red[wave] = loc;
    __syncthreads();
    if (t == 0) atomicAdd(&acc4[b], red[0] + red[1] + red[2] + red[3]);
  }
}

// ---- finish with inline dtype detect ----
__global__ void k_finish(const float* __restrict__ acc4, const u16* __restrict__ x16,
                         void* __restrict__ out){
  __shared__ int flg;
  int t = threadIdx.x;   // 64 threads
  if (t == 0) flg = 0;
  __syncthreads();
  int hit = 0;
  for (int k = t; k < 512; k += 64){
    u16 u = x16[k];
    if (((u >> 7) & 0xFF) >= 0x90) hit = 1;
  }
  if (hit) flg = 1;
  __syncthreads();
  if (t < NB){
    float v = acc4[t] * (1.0f/1048576.0f);
    if (flg) ((float*)out)[t] = v;
    else     ((u16*)out)[t] = f2b(v);
  }
}

extern "C" void kernel_launch(void* const* d_in, const int* in_sizes, int n_in,
                              void* d_out, int out_size, void* d_ws, size_t ws_size,
                              hipStream_t stream)
{
  const void* x   = d_in[0];
  const void* ew  = d_in[1];
  const void* c1  = d_in[2];
  const void* b1  = d_in[3];
  const void* c2  = d_in[4];
  const void* b2  = d_in[5];
  const int* ei  = (const int*)d_in[6];
  const int* bat = (const int*)d_in[7];
  const int E = in_sizes[1];

  char* wsb = (char*)d_ws;
  float* A    = (float*)(wsb + OFF_A);
  float* acc4 = (float*)(wsb + OFF_ACC);
  float* AAt  = (float*)(wsb + OFF_AAT);
  float* rA   = (float*)(wsb + OFF_RA);
  float* W    = (float*)(wsb + OFF_W);
  float* RM   = (float*)(wsb + OFF_RM);
  float* CM   = (float*)(wsb + OFF_CM);
  float* RX   = (float*)(wsb + OFF_RX);
  float* CXv  = (float*)(wsb + OFF_CX);
  float* bfv  = (float*)(wsb + OFF_BF);
  u16* ATb = (u16*)(wsb + OFF_ATB);
  u16* Wb  = (u16*)(wsb + OFF_WB);
  u16* X2  = (u16*)(wsb + OFF_X2);
  u16* Xt  = (u16*)(wsb + OFF_XT);
  u16* Ua  = (u16*)(wsb + OFF_UA);
  u16* Ub  = (u16*)(wsb + OFF_UB);
  u16* Uc  = (u16*)(wsb + OFF_UC);
  u16* Ud  = (u16*)(wsb + OFF_UD);
  float* Yacc = (float*)(wsb + OFF_YACC);
  float* xf   = (float*)(wsb + OFF_XF);
  float* ewf  = (float*)(wsb + OFF_EWF);
  float* cf   = (float*)(wsb + OFF_CF);

  hipMemsetAsync(wsb, 0, OFF_AAT, stream);   // zero A + acc4

  k_convert<<<dim3(737), dim3(256), 0, stream>>>(x, ew, c1, c2, b1, b2, xf, ewf, cf, bfv);
  k_setup<<<dim3(2656), dim3(256), 0, stream>>>(ei, bat, ewf, A, E, xf, Xt, cf, W, Wb);
  k_prepA<<<dim3(10, NB), dim3(256), 0, stream>>>(A, AAt, ATb, rA);

  for (int L = 0; L < 2; L++){
    const float* Wl = W + (size_t)L*1152*64;
    const u16*  Wbl = Wb + (size_t)L*10*64*64;
    if (L == 1)
      k_xt<<<dim3(256, NB), dim3(256), 0, stream>>>(X2, Xt);
    k_mixrow<<<dim3(320, NB), dim3(256), 0, stream>>>(Xt, A, AAt, rA, Wbl,
                                                      Ua, Ub, Uc, Ud, Yacc, RM, CM, RX, CXv);
    k_tne<<<dim3(2, 256), dim3(256), 0, stream>>>(ATb, Ua, Ub, Uc, Ud, Yacc, Wl,
                                                  RM, CM, RX, CXv, bfv + L*64, X2, acc4, L);
  }
  k_finish<<<dim3(1), dim3(64), 0, stream>>>(acc4, (const u16*)x, d_out);
}

// Round 13
// 234.085 us; speedup vs baseline: 1.2687x; 1.0106x over previous
//
#include <hip/hip_runtime.h>
#include <stdint.h>

typedef unsigned short u16;
using short8 = __attribute__((ext_vector_type(8))) short;
using f32x4  = __attribute__((ext_vector_type(4))) float;

#define NB 4
#define NN 128
#define NF 32
#define ND 64
#define NMAT (NB*ND*NN*NN)   // 4,194,304

// ---- workspace byte offsets ----
#define OFF_A     0u
#define OFF_ACC   262144u
#define OFF_AAT   262400u
#define OFF_RA    524544u
#define OFF_W     526592u
#define OFF_RM    1116416u
#define OFF_CM    1247488u
#define OFF_RX    1378560u
#define OFF_CX    1509632u
#define OFF_BF    1640960u
#define OFF_ATB   1641472u
#define OFF_WB    1772544u
#define OFF_X2    1936384u
#define OFF_XT    10324992u
#define OFF_UA    18713600u
#define OFF_UB    27102208u
#define OFF_UC    35490816u
#define OFF_UD    43879424u
#define OFF_YACC  52268032u
#define OFF_XF    (OFF_YACC)
#define OFF_EWF   (OFF_YACC + 65536u)
#define OFF_CF    (OFF_YACC + 98304u)

__device__ __forceinline__ float b2f(u16 v){
  union { uint32_t u; float f; } x; x.u = ((uint32_t)v) << 16; return x.f;
}
__device__ __forceinline__ u16 f2b(float f){
  union { uint32_t u; float f2; } x; x.f2 = f;
  uint32_t u = x.u;
  return (u16)((u + 0x7FFFu + ((u >> 16) & 1u)) >> 16);
}

#define MFMA16(a,b,c) __builtin_amdgcn_mfma_f32_16x16x32_bf16((a),(b),(c),0,0,0)

__device__ __constant__ signed char dR1[18] = {0,9,1,10,2,3,4,13,14,19,5,7,15,18,6,8,16,17};
__device__ __constant__ signed char dR2[18] = {-1,11,-1,12,-1,-1,-1,-1,-1,-1,-1,-1,-1,-1,-1,-1,-1,-1};

// ---- convert with per-block local dtype detect ----
__global__ void k_convert(const void* __restrict__ xs, const void* __restrict__ ews,
                          const void* __restrict__ c1s, const void* __restrict__ c2s,
                          const void* __restrict__ b1s, const void* __restrict__ b2s,
                          float* __restrict__ xf, float* __restrict__ ewf,
                          float* __restrict__ cf, float* __restrict__ bfv){
  __shared__ int flg;
  const u16* x16 = (const u16*)xs;
  if (threadIdx.x == 0) flg = 0;
  __syncthreads();
  int hit = 0;
  for (int k = threadIdx.x; k < 1024; k += 256){
    u16 u = x16[k];
    if (((u >> 7) & 0xFF) >= 0x90) hit = 1;
  }
  if (hit) flg = 1;
  __syncthreads();
  const int isf = flg;

  int t = blockIdx.x*256 + threadIdx.x;
  if (t >= 188544) return;
  const void* src; int idx; float* dst;
  if (t < 16384)      { src = xs;  idx = t;          dst = xf + idx; }
  else if (t < 24576) { src = ews; idx = t - 16384;  dst = ewf + idx; }
  else if (t < 106496){ src = c1s; idx = t - 24576;  dst = cf + idx; }
  else if (t < 188416){ src = c2s; idx = t - 106496; dst = cf + 81920 + idx; }
  else if (t < 188480){ src = b1s; idx = t - 188416; dst = bfv + idx; }
  else                { src = b2s; idx = t - 188480; dst = bfv + 64 + idx; }
  float v = isf ? ((const float*)src)[idx] : b2f(((const u16*)src)[idx]);
  *dst = v;
}

// ---- fused setup: scatter | makeXt1 | buildW ----
__global__ void k_setup(const int* __restrict__ ei, const int* __restrict__ bat,
                        const float* __restrict__ ewf, float* __restrict__ A, int E,
                        const float* __restrict__ xf, u16* __restrict__ Xt,
                        const float* __restrict__ cf, float* __restrict__ W,
                        u16* __restrict__ Wb){
  const int bx = blockIdx.x;
  if (bx < 32){
    for (int t = bx*256 + threadIdx.x; t < E; t += 32*256){
      int s = ei[t], dnode = ei[E + t];
      int g = bat[s];
      int r = s - g*NN, c = dnode - g*NN;
      atomicAdd(&A[(g*NN + r)*NN + c], ewf[t]);
    }
  } else if (bx < 32 + 2048){
    int gid = (bx - 32)*256 + threadIdx.x;
    if (gid >= NMAT/8) return;
    int d0 = (gid & 7)*8;
    int ij = (gid >> 3) & 16383;
    int b  = gid >> 17;
    int i = ij >> 7, j = ij & 127;
    const float* src = (d0 < NF) ? &xf[(b*NN + i)*NF + d0] : &xf[(b*NN + j)*NF + (d0 - NF)];
    float4 f0 = *(const float4*)src;
    float4 f1 = *(const float4*)(src + 4);
    short8 v;
    v[0]=(short)f2b(f0.x); v[1]=(short)f2b(f0.y); v[2]=(short)f2b(f0.z); v[3]=(short)f2b(f0.w);
    v[4]=(short)f2b(f1.x); v[5]=(short)f2b(f1.y); v[6]=(short)f2b(f1.z); v[7]=(short)f2b(f1.w);
    *(short8*)(Xt + ((size_t)(b*16384 + ij))*64 + d0) = v;
  } else {
    int gl = (bx - 2080)*256 + threadIdx.x;
    if (gl >= 2*1152*64) return;
    int L = gl / (1152*64);
    int rem = gl - L*1152*64;
    int row = rem >> 6, e = rem & 63;
    int slot = row >> 6, d = row & 63;
    const float* cc = cf + L*81920;
    int base = (d*64 + e)*20;
    float v = cc[base + dR1[slot]];
    if (dR2[slot] >= 0) v += cc[base + dR2[slot]];
    float scale = (slot == 9) ? 1.0f : (1.0f/128.0f);
    v *= scale;
    W[gl] = v;
    if (slot < 10)
      Wb[(((size_t)L*10 + slot)*64 + e)*64 + d] = f2b(v);
  }
}

// ---- fused A-processing: iq<8 = AAt slices | iq==8 = ATb transpose | iq==9 = rA ----
__global__ __launch_bounds__(256) void k_prepA(const float* __restrict__ A, float* __restrict__ AAt,
                                               u16* __restrict__ ATb, float* __restrict__ rA){
  const int iq = blockIdx.x, b = blockIdx.y;
  const int t = threadIdx.x;
  if (iq < 8){
    int j = t & 127, ih = t >> 7;
    const float* Ab = A + b*NN*NN;
    float acc[8] = {0,0,0,0,0,0,0,0};
    for (int k = 0; k < NN; k++){
      float aj = Ab[j*NN + k];
      #pragma unroll
      for (int ii = 0; ii < 8; ii++){
        int i = iq*16 + ih*8 + ii;
        acc[ii] += Ab[i*NN + k] * aj;
      }
    }
    #pragma unroll
    for (int ii = 0; ii < 8; ii++){
      int i = iq*16 + ih*8 + ii;
      AAt[(b*NN + i)*NN + j] = acc[ii];
    }
  } else if (iq == 8){
    __shared__ float lds[128][129];
    for (int l = 0; l < 64; l++){
      int idx = l*256 + t;
      lds[idx >> 7][idx & 127] = A[b*16384 + idx];
    }
    __syncthreads();
    for (int l = 0; l < 64; l++){
      int idx = l*256 + t;
      int r = idx >> 7, c = idx & 127;
      ATb[b*16384 + idx] = f2b(lds[c][r]);
    }
  } else {
    if (t < 128){
      const float* Ab = A + (b*NN + t)*NN;
      float s = 0.f;
      for (int j = 0; j < 128; j++) s += Ab[j];
      rA[b*NN + t] = s;
    }
  }
}

// ---- X2[b][e][ij] -> Xt[b][ij][e] via LDS tiles ----
__global__ __launch_bounds__(256) void k_xt(const u16* __restrict__ X, u16* __restrict__ Xt){
  int b = blockIdx.y;
  int ij0 = blockIdx.x*64;
  __shared__ u16 lds[64][65];
  int t = threadIdx.x;
  #pragma unroll
  for (int l = 0; l < 2; l++){
    int idx = l*2048 + t*8;
    int d = idx >> 6, c = idx & 63;
    const u16* p = X + ((size_t)(b*64 + d))*16384 + ij0 + c;
    short8 v = *(const short8*)p;
    #pragma unroll
    for (int k = 0; k < 8; k++) lds[d][c + k] = (u16)v[k];
  }
  __syncthreads();
  #pragma unroll
  for (int l = 0; l < 2; l++){
    int idx = l*2048 + t*8;
    int r = idx >> 6, c = idx & 63;
    short8 v;
    #pragma unroll
    for (int k = 0; k < 8; k++) v[k] = (short)lds[c + k][r];
    *(short8*)(Xt + ((size_t)(b*16384 + ij0 + r))*64 + c) = v;
  }
}

#define SJ32 70   // u32 stride, bf16-pair staging (was 72; shaved for 3 blocks/CU)
#define SJF  67   // fp32 stride, Yacc staging (was 69)

// ---- fused: mix (bx<256) | rowcol (bx>=256) ----
__global__ __launch_bounds__(256) void k_mixrow(const u16* __restrict__ Xt, const float* __restrict__ A,
    const float* __restrict__ AAt, const float* __restrict__ rA, const u16* __restrict__ Wb,
    u16* __restrict__ Ua, u16* __restrict__ Ub, u16* __restrict__ Uc, u16* __restrict__ Ud,
    float* __restrict__ Yacc,
    float* __restrict__ RM, float* __restrict__ CM,
    float* __restrict__ RX, float* __restrict__ CXv)
{
  const int b = blockIdx.y;
  const int t = threadIdx.x;

  if (blockIdx.x >= 256){
    int d = t & 63;
    int task = (blockIdx.x - 256)*4 + (t >> 6);
    float sm = 0.f, sx = 0.f;
    if (task < 128){
      int i = task;
      for (int j = 0; j < 128; j++){
        float xv = b2f(Xt[((size_t)(b*16384 + i*128 + j))*64 + d]);
        float av = A[b*16384 + i*128 + j];
        sm += xv*av; sx += xv;
      }
      RM[(b*64 + d)*128 + i] = sm;
      RX[(b*64 + d)*128 + i] = sx;
    } else {
      int j = task - 128;
      for (int i = 0; i < 128; i++){
        float xv = b2f(Xt[((size_t)(b*16384 + i*128 + j))*64 + d]);
        float av = A[b*16384 + i*128 + j];
        sm += xv*av; sx += xv;
      }
      CM[(b*64 + d)*128 + j] = sm;
      CXv[(b*64 + d)*128 + j] = sx;
    }
    return;
  }

  const int w = t >> 6, lane = t & 63;
  const int col = lane & 15, quad = lane >> 4;
  const int ij0 = blockIdx.x*64;

  __shared__ uint32_t lsb[4][32*SJ32];
  __shared__ float lsf[64*SJF];

  short8 wa[10][2];
  #pragma unroll
  for (int s = 0; s < 10; s++){
    const u16* wp = Wb + (size_t)((s*64 + w*16 + col)*64 + quad*8);
    wa[s][0] = *(const short8*)wp;
    wa[s][1] = *(const short8*)(wp + 32);
  }
  short8 xb[4][2];
  #pragma unroll
  for (int sj = 0; sj < 4; sj++){
    const u16* xp = Xt + ((size_t)(b*16384 + ij0 + sj*16 + col))*64 + quad*8;
    xb[sj][0] = *(const short8*)xp;
    xb[sj][1] = *(const short8*)(xp + 32);
  }
  float a_s[4], t_s[4], rjv[4];
  #pragma unroll
  for (int sj = 0; sj < 4; sj++){
    int ij = ij0 + sj*16 + col;
    a_s[sj] = A[b*16384 + ij];
    t_s[sj] = AAt[b*16384 + ij];
    rjv[sj] = rA[b*128 + (ij & 127)];
  }
  const float riv = rA[b*128 + (ij0 >> 7)];

  #pragma unroll
  for (int g = 0; g < 5; g++){
    const int s0_tab[5]  = {0, 2, 4, 5, 6};
    const int nsl_tab[5] = {2, 2, 1, 1, 4};
    const int s0 = s0_tab[g], nsl = nsl_tab[g];
    #pragma unroll
    for (int sj = 0; sj < 4; sj++){
      f32x4 acc[4];
      #pragma unroll
      for (int s = 0; s < 4; s++) acc[s] = (f32x4){0.f,0.f,0.f,0.f};
      #pragma unroll
      for (int s = 0; s < 4; s++){
        if (s >= nsl) break;
        acc[s] = MFMA16(wa[s0+s][0], xb[sj][0], acc[s]);
        acc[s] = MFMA16(wa[s0+s][1], xb[sj][1], acc[s]);
      }
      if (g < 4){
        float v[4];
        #pragma unroll
        for (int r = 0; r < 4; r++){
          if (g == 2 || g == 3) v[r] = acc[0][r]*a_s[sj];
          else                  v[r] = acc[0][r]*a_s[sj] + acc[1][r];
        }
        uint32_t p0 = (uint32_t)f2b(v[0]) | ((uint32_t)f2b(v[1]) << 16);
        uint32_t p1 = (uint32_t)f2b(v[2]) | ((uint32_t)f2b(v[3]) << 16);
        int ep = w*8 + quad*2;
        lsb[g][ep*SJ32 + sj*16 + col] = p0;
        lsb[g][(ep + 1)*SJ32 + sj*16 + col] = p1;
      } else {
        #pragma unroll
        for (int r = 0; r < 4; r++){
          float v = acc[0][r]*t_s[sj] + acc[1][r]*riv + acc[2][r]*rjv[sj] + acc[3][r];
          lsf[(w*16 + quad*4 + r)*SJF + sj*16 + col] = v;
        }
      }
    }
  }
  __syncthreads();

  const int eo = t >> 2, seg = t & 3;
  const int ep = eo >> 1, sh = (eo & 1)*16;
  #pragma unroll
  for (int g = 0; g < 4; g++){
    const uint32_t* lp = &lsb[g][ep*SJ32 + seg*16];
    short8 v0, v1;
    #pragma unroll
    for (int k = 0; k < 8; k++){
      v0[k] = (short)((lp[k]   >> sh) & 0xffffu);
      v1[k] = (short)((lp[8+k] >> sh) & 0xffffu);
    }
    u16* U = (g==0)?Ua:(g==1)?Ub:(g==2)?Uc:Ud;
    u16* dst = U + ((size_t)(b*64 + eo) << 14) + ij0 + seg*16;
    *(short8*)dst = v0;
    *(short8*)(dst + 8) = v1;
  }
  {
    const float* fp = &lsf[eo*SJF + seg*16];
    float* dst = Yacc + ((size_t)(b*64 + eo) << 14) + ij0 + seg*16;
    #pragma unroll
    for (int q = 0; q < 4; q++)
      *(float4*)(dst + q*4) = make_float4(fp[q*4], fp[q*4+1], fp[q*4+2], fp[q*4+3]);
  }
}

#define SLT 68   // uint32 stride for in-kernel transpose staging (b128 reads 2-way max)

// ---- fused: in-LDS transposes + four A-products + Yacc + broadcast + bias + sigmoid/reduce ----
__global__ __launch_bounds__(256) void k_tne(const u16* __restrict__ ATb,
    const u16* __restrict__ Ua, const u16* __restrict__ Ub,
    const u16* __restrict__ Uc, const u16* __restrict__ Ud,
    const float* __restrict__ Yacc, const float* __restrict__ W,
    const float* __restrict__ RM, const float* __restrict__ CM,
    const float* __restrict__ RX, const float* __restrict__ CXv,
    const float* __restrict__ bias, u16* __restrict__ Xout, float* __restrict__ acc4, int last)
{
  const int nh = blockIdx.x, be = blockIdx.y;
  const int b = be >> 6, e = be & 63;
  const int t = threadIdx.x, wave = t >> 6, lane = t & 63;
  const int col = lane & 15, quad = lane >> 4;
  const int m0 = (wave >> 1)*64;
  const int n0 = nh*64 + (wave & 1)*32;
  const int nb0 = nh*64;

  __shared__ uint32_t uls[128*SLT];
  __shared__ uint32_t ubl[64*SLT];
  __shared__ float radd[128], cadd[128];
  __shared__ float red[4];

  if (t < 128){
    int i = t; float s = 0.f;
    for (int d = 0; d < ND; d++){
      int v = (b*ND + d)*NN + i;
      s += W[(640 + d)*64 + e]*RM[v] + W[(704 + d)*64 + e]*CM[v]
         + W[(768 + d)*64 + e]*RX[v] + W[(832 + d)*64 + e]*CXv[v];
    }
    radd[i] = s;
  } else {
    int j = t - 128; float s = 0.f;
    for (int d = 0; d < ND; d++){
      int v = (b*ND + d)*NN + j;
      s += W[(896 + d)*64 + e]*RM[v] + W[(960 + d)*64 + e]*CM[v]
         + W[(1024 + d)*64 + e]*RX[v] + W[(1088 + d)*64 + e]*CXv[v];
    }
    cadd[j] = s;
  }

  const u16* ua = Ua + ((size_t)be << 14);
  const u16* ub = Ub + ((size_t)be << 14);
  {
    const int kp = t >> 2;
    #pragma unroll
    for (int it = 0; it < 4; it++){
      int mo = it*4 + (t & 3);
      short8 r0 = *(const short8*)(ua + (2*kp)*128 + mo*8);
      short8 r1 = *(const short8*)(ua + (2*kp + 1)*128 + mo*8);
      #pragma unroll
      for (int x = 0; x < 8; x++)
        uls[(mo*8 + x)*SLT + kp] = ((uint32_t)(u16)r0[x]) | (((uint32_t)(u16)r1[x]) << 16);
    }
    #pragma unroll
    for (int it = 0; it < 2; it++){
      int no = it*4 + (t & 3);
      short8 r0 = *(const short8*)(ub + (2*kp)*128 + nb0 + no*8);
      short8 r1 = *(const short8*)(ub + (2*kp + 1)*128 + nb0 + no*8);
      #pragma unroll
      for (int x = 0; x < 8; x++)
        ubl[(no*8 + x)*SLT + kp] = ((uint32_t)(u16)r0[x]) | (((uint32_t)(u16)r1[x]) << 16);
    }
  }
  __syncthreads();

  f32x4 acc[4][2];
  #pragma unroll
  for (int mt = 0; mt < 4; mt++)
    #pragma unroll
    for (int nt = 0; nt < 2; nt++)
      acc[mt][nt] = (f32x4){0.f,0.f,0.f,0.f};

  const u16* at = ATb + ((size_t)b << 14);
  short8 at_n[4][2];
  #pragma unroll
  for (int kq = 0; kq < 4; kq++){
    int k0 = kq*32 + quad*8;
    at_n[kq][0] = *(const short8*)(at + (n0 + col)*128 + k0);
    at_n[kq][1] = *(const short8*)(at + (n0 + 16 + col)*128 + k0);
  }

  // f0: Ua^T · A
  #pragma unroll
  for (int kq = 0; kq < 4; kq++){
    int kd = kq*16 + quad*4;
    #pragma unroll
    for (int mt = 0; mt < 4; mt++){
      short8 af = *(const short8*)&uls[(m0 + mt*16 + col)*SLT + kd];
      acc[mt][0] = MFMA16(af, at_n[kq][0], acc[mt][0]);
      acc[mt][1] = MFMA16(af, at_n[kq][1], acc[mt][1]);
    }
  }
  // f1: A^T · Ub
  #pragma unroll
  for (int kq = 0; kq < 4; kq++){
    int k0 = kq*32 + quad*8, kd = kq*16 + quad*4;
    short8 bf0 = *(const short8*)&ubl[((wave & 1)*32 + 0*16 + col)*SLT + kd];
    short8 bf1 = *(const short8*)&ubl[((wave & 1)*32 + 1*16 + col)*SLT + kd];
    #pragma unroll
    for (int mt = 0; mt < 4; mt++){
      short8 af = *(const short8*)(at + (m0 + mt*16 + col)*128 + k0);
      acc[mt][0] = MFMA16(af, bf0, acc[mt][0]);
      acc[mt][1] = MFMA16(af, bf1, acc[mt][1]);
    }
  }
  // f2: Uc · A
  {
    const u16* uc = Uc + ((size_t)be << 14);
    #pragma unroll
    for (int kq = 0; kq < 4; kq++){
      int k0 = kq*32 + quad*8;
      #pragma unroll
      for (int mt = 0; mt < 4; mt++){
        short8 af = *(const short8*)(uc + (m0 + mt*16 + col)*128 + k0);
        acc[mt][0] = MFMA16(af, at_n[kq][0], acc[mt][0]);
        acc[mt][1] = MFMA16(af, at_n[kq][1], acc[mt][1]);
      }
    }
  }
  // f3: (Ud · A)^T
  {
    const u16* ud = Ud + ((size_t)be << 14);
    #pragma unroll
    for (int kq = 0; kq < 4; kq++){
      int k0 = kq*32 + quad*8;
      short8 bf0 = *(const short8*)(ud + (n0 + col)*128 + k0);
      short8 bf1 = *(const short8*)(ud + (n0 + 16 + col)*128 + k0);
      #pragma unroll
      for (int mt = 0; mt < 4; mt++){
        short8 af = *(const short8*)(at + (m0 + mt*16 + col)*128 + k0);
        acc[mt][0] = MFMA16(af, bf0, acc[mt][0]);
        acc[mt][1] = MFMA16(af, bf1, acc[mt][1]);
      }
    }
  }
  __syncthreads();

  uint32_t* stg = uls;
  const float bv = bias[e];
  const float* Y = Yacc + ((size_t)be << 14);
  if (!last){
    #pragma unroll
    for (int mt = 0; mt < 4; mt++)
      #pragma unroll
      for (int nt = 0; nt < 2; nt++)
        #pragma unroll
        for (int rp = 0; rp < 2; rp++){
          uint32_t p = 0;
          #pragma unroll
          for (int h = 0; h < 2; h++){
            int r = rp*2 + h;
            int row = m0 + mt*16 + quad*4 + r;
            int cn = n0 + nt*16 + col;
            float v = acc[mt][nt][r] + Y[row*128 + cn] + radd[row] + cadd[cn] + bv;
            v = 1.f/(1.f + __expf(-v));
            p |= ((uint32_t)f2b(v)) << (16*h);
          }
          int ipair = (m0 + mt*16 + quad*4) >> 1;
          stg[(ipair + rp)*SLT + (wave & 1)*32 + nt*16 + col] = p;
        }
    __syncthreads();
    const uint32_t* lp = &stg[(t >> 2)*SLT + (t & 1)*32];
    const int sh = ((t >> 1) & 1)*16;
    u16* dst = Xout + ((size_t)be << 14) + (size_t)(t >> 1)*128 + nh*64 + (t & 1)*32;
    #pragma unroll
    for (int q2 = 0; q2 < 4; q2++){
      short8 v;
      #pragma unroll
      for (int k = 0; k < 8; k++) v[k] = (short)((lp[q2*8 + k] >> sh) & 0xffffu);
      *(short8*)(dst + q2*8) = v;
    }
  } else {
    float loc = 0.f;
    #pragma unroll
    for (int mt = 0; mt < 4; mt++)
      #pragma unroll
      for (int nt = 0; nt < 2; nt++)
        #pragma unroll
        for (int r = 0; r < 4; r++){
          int row = m0 + mt*16 + quad*4 + r;
          int cn = n0 + nt*16 + col;
          loc += acc[mt][nt][r] + Y[row*128 + cn] + radd[row] + cadd[cn] + bv;
        }
    for (int off = 32; off > 0; off >>= 1) loc += __shfl_down(loc, off, 64);
    if (lane == 0) red[wave] = loc;
    __syncthreads();
    if (t == 0) atomicAdd(&acc4[b], red[0] + red[1] + red[2] + red[3]);
  }
}

// ---- finish with inline dtype detect ----
__global__ void k_finish(const float* __restrict__ acc4, const u16* __restrict__ x16,
                         void* __restrict__ out){
  __shared__ int flg;
  int t = threadIdx.x;
  if (t == 0) flg = 0;
  __syncthreads();
  int hit = 0;
  for (int k = t; k < 512; k += 64){
    u16 u = x16[k];
    if (((u >> 7) & 0xFF) >= 0x90) hit = 1;
  }
  if (hit) flg = 1;
  __syncthreads();
  if (t < NB){
    float v = acc4[t] * (1.0f/1048576.0f);
    if (flg) ((float*)out)[t] = v;
    else     ((u16*)out)[t] = f2b(v);
  }
}

extern "C" void kernel_launch(void* const* d_in, const int* in_sizes, int n_in,
                              void* d_out, int out_size, void* d_ws, size_t ws_size,
                              hipStream_t stream)
{
  const void* x   = d_in[0];
  const void* ew  = d_in[1];
  const void* c1  = d_in[2];
  const void* b1  = d_in[3];
  const void* c2  = d_in[4];
  const void* b2  = d_in[5];
  const int* ei  = (const int*)d_in[6];
  const int* bat = (const int*)d_in[7];
  const int E = in_sizes[1];

  char* wsb = (char*)d_ws;
  float* A    = (float*)(wsb + OFF_A);
  float* acc4 = (float*)(wsb + OFF_ACC);
  float* AAt  = (float*)(wsb + OFF_AAT);
  float* rA   = (float*)(wsb + OFF_RA);
  float* W    = (float*)(wsb + OFF_W);
  float* RM   = (float*)(wsb + OFF_RM);
  float* CM   = (float*)(wsb + OFF_CM);
  float* RX   = (float*)(wsb + OFF_RX);
  float* CXv  = (float*)(wsb + OFF_CX);
  float* bfv  = (float*)(wsb + OFF_BF);
  u16* ATb = (u16*)(wsb + OFF_ATB);
  u16* Wb  = (u16*)(wsb + OFF_WB);
  u16* X2  = (u16*)(wsb + OFF_X2);
  u16* Xt  = (u16*)(wsb + OFF_XT);
  u16* Ua  = (u16*)(wsb + OFF_UA);
  u16* Ub  = (u16*)(wsb + OFF_UB);
  u16* Uc  = (u16*)(wsb + OFF_UC);
  u16* Ud  = (u16*)(wsb + OFF_UD);
  float* Yacc = (float*)(wsb + OFF_YACC);
  float* xf   = (float*)(wsb + OFF_XF);
  float* ewf  = (float*)(wsb + OFF_EWF);
  float* cf   = (float*)(wsb + OFF_CF);

  hipMemsetAsync(wsb, 0, OFF_AAT, stream);   // zero A + acc4

  k_convert<<<dim3(737), dim3(256), 0, stream>>>(x, ew, c1, c2, b1, b2, xf, ewf, cf, bfv);
  k_setup<<<dim3(2656), dim3(256), 0, stream>>>(ei, bat, ewf, A, E, xf, Xt, cf, W, Wb);
  k_prepA<<<dim3(10, NB), dim3(256), 0, stream>>>(A, AAt, ATb, rA);

  for (int L = 0; L < 2; L++){
    const float* Wl = W + (size_t)L*1152*64;
    const u16*  Wbl = Wb + (size_t)L*10*64*64;
    if (L == 1)
      k_xt<<<dim3(256, NB), dim3(256), 0, stream>>>(X2, Xt);
    k_mixrow<<<dim3(320, NB), dim3(256), 0, stream>>>(Xt, A, AAt, rA, Wbl,
                                                      Ua, Ub, Uc, Ud, Yacc, RM, CM, RX, CXv);
    k_tne<<<dim3(2, 256), dim3(256), 0, stream>>>(ATb, Ua, Ub, Uc, Ud, Yacc, Wl,
                                                  RM, CM, RX, CXv, bfv + L*64, X2, acc4, L);
  }
  k_finish<<<dim3(1), dim3(64), 0, stream>>>(acc4, (const u16*)x, d_out);
}